// Round 2
// baseline (195.513 us; speedup 1.0000x reference)
//
#include <hip/hip_runtime.h>
#include <math.h>

typedef unsigned short u16;
typedef unsigned int u32;
typedef __bf16 bfrag8 __attribute__((ext_vector_type(8)));
typedef float f32x4 __attribute__((ext_vector_type(4)));

#define B_ 2
#define T_ 2048
#define H_ 16
#define D_ 64
#define C_ 1024
#define NQKV_ 3072

#define MFMA_BF16(a, b, c) __builtin_amdgcn_mfma_f32_16x16x32_bf16((a), (b), (c), 0, 0, 0)

__device__ __forceinline__ u16 f2bf(float f) {
  u32 u = __builtin_bit_cast(u32, f);
  u += 0x7fffu + ((u >> 16) & 1u);  // RNE
  return (u16)(u >> 16);
}

// async global->LDS, 16B/lane; lds dest = wave-uniform base + lane*16
__device__ __forceinline__ void load_lds16(const u16* gp, u16* lp) {
  __builtin_amdgcn_global_load_lds(
      (const __attribute__((address_space(1))) u32*)(const void*)gp,
      (__attribute__((address_space(3))) u32*)(void*)lp, 16, 0, 0);
}

// raw barrier with compiler motion fences (keep ds_reads inside their phase)
__device__ __forceinline__ void block_barrier() {
  __builtin_amdgcn_sched_barrier(0);
  asm volatile("" ::: "memory");
  __builtin_amdgcn_s_barrier();
  asm volatile("" ::: "memory");
  __builtin_amdgcn_sched_barrier(0);
}

// -------- convert x (f32) -> bf16 --------
__global__ __launch_bounds__(256) void convert_x(const float* __restrict__ src,
                                                 u16* __restrict__ dst) {
  size_t i = ((size_t)blockIdx.x * 256 + threadIdx.x) * 8;
  const float* s = src + i;
  float4 a = *(const float4*)s, b = *(const float4*)(s + 4);
  union { uint4 v; u16 h[8]; } t;
  t.h[0] = f2bf(a.x); t.h[1] = f2bf(a.y); t.h[2] = f2bf(a.z); t.h[3] = f2bf(a.w);
  t.h[4] = f2bf(b.x); t.h[5] = f2bf(b.y); t.h[6] = f2bf(b.z); t.h[7] = f2bf(b.w);
  *(uint4*)(dst + i) = t.v;
}

// -------- transpose+convert weight: src f32 [K][N] -> dst bf16 [N][K] --------
__global__ __launch_bounds__(256) void transpose_w(const float* __restrict__ src,
                                                   u16* __restrict__ dst, int K, int N) {
  __shared__ u16 tile[64][65];
  int bx = blockIdx.x * 64;  // over N
  int by = blockIdx.y * 64;  // over K
  for (int idx = threadIdx.x; idx < 4096; idx += 256) {
    int r = idx >> 6, c = idx & 63;
    tile[r][c] = f2bf(src[(size_t)(by + r) * N + bx + c]);
  }
  __syncthreads();
  for (int idx = threadIdx.x; idx < 4096; idx += 256) {
    int r = idx >> 6, c = idx & 63;
    dst[(size_t)(bx + r) * K + by + c] = tile[c][r];
  }
}

// -------- GEMM 1: qkv = X(4096x1024)bf16 @ WT(3072x1024)bf16, RoPE(+q*1/8) epilogue.
// 256x256 tile, BK=64, 8 waves (2Mx4N), 8-phase-style schedule:
//   per K-tile: 4 quadrant phases {ds_read subtile; 16 MFMA (setprio-wrapped); barrier},
//   next K-tile's 8 global_load_lds issued at P0 + counted s_waitcnt vmcnt(8)
//   (loads stay in flight across barriers; never drained to 0 in main loop).
// LDS chunk-XOR swizzle: LDS[row][c] holds global 16B-chunk c^(row&7); staging source
// pre-swizzled, ds_read address swizzled with same involution -> conflict-free b128. --------
#define QKV_STAGE(kt, b)                                               \
  {                                                                    \
    _Pragma("unroll") for (int l = 0; l < 4; l++) {                    \
      load_lds16(gA + (size_t)(l * 64) * C_ + (kt) * 64,               \
                 &As[b][(l * 64 + wave * 8) * 64]);                    \
      load_lds16(gB + (size_t)(l * 64) * C_ + (kt) * 64,               \
                 &Bs[b][(l * 64 + wave * 8) * 64]);                    \
    }                                                                  \
  }

#define QKV_LOADA(i0)                                                            \
  {                                                                              \
    _Pragma("unroll") for (int ii = 0; ii < 4; ii++) {                           \
      af[ii][0] = *(const bfrag8*)&as_[(rA + ((i0) + ii) * 16) * 64 + cofs0];    \
      af[ii][1] = *(const bfrag8*)&as_[(rA + ((i0) + ii) * 16) * 64 + cofs1];    \
    }                                                                            \
  }

#define QKV_LOADB(j0)                                                            \
  {                                                                              \
    _Pragma("unroll") for (int jj = 0; jj < 2; jj++) {                           \
      bf[jj][0] = *(const bfrag8*)&bs_[(rB + ((j0) + jj) * 16) * 64 + cofs0];    \
      bf[jj][1] = *(const bfrag8*)&bs_[(rB + ((j0) + jj) * 16) * 64 + cofs1];    \
    }                                                                            \
  }

#define QKV_MMA(i0, j0)                                                          \
  {                                                                              \
    __builtin_amdgcn_s_setprio(1);                                               \
    _Pragma("unroll") for (int ii = 0; ii < 4; ii++)                             \
        _Pragma("unroll") for (int jj = 0; jj < 2; jj++) {                       \
      acc[(i0) + ii][(j0) + jj] =                                                \
          MFMA_BF16(af[ii][0], bf[jj][0], acc[(i0) + ii][(j0) + jj]);            \
      acc[(i0) + ii][(j0) + jj] =                                                \
          MFMA_BF16(af[ii][1], bf[jj][1], acc[(i0) + ii][(j0) + jj]);            \
    }                                                                            \
    __builtin_amdgcn_s_setprio(0);                                               \
  }

__global__ __launch_bounds__(512) void gemm_qkv_rope(const u16* __restrict__ X,
                                                     const u16* __restrict__ WT,
                                                     u16* __restrict__ qb,
                                                     u16* __restrict__ kb,
                                                     u16* __restrict__ vb) {
  const int NT = 16;  // K / 64
  __shared__ __align__(16) u16 As[2][256 * 64];
  __shared__ __align__(16) u16 Bs[2][256 * 64];
  int tid = threadIdx.x;
  int lane = tid & 63, wave = tid >> 6;
  int quad = lane >> 4, lr = lane & 15;
  int wm = wave >> 2, wn = wave & 3;
  int m0 = blockIdx.y * 256, n0 = blockIdx.x * 256;

  // staging source: LDS linear dest (row = wave*8 + lane>>3, chunk = lane&7),
  // global source chunk = (lane&7) ^ (row&7)  (row&7 == lane>>3)
  int srow = lane >> 3;
  int schunk = (lane & 7) ^ srow;
  const u16* gA = X + (size_t)(m0 + wave * 8 + srow) * C_ + schunk * 8;
  const u16* gB = WT + (size_t)(n0 + wave * 8 + srow) * C_ + schunk * 8;

  // read side: logical (row, chunk c) lives at LDS chunk c ^ (row&7); row&7 == lr&7
  int rA = wm * 128 + lr;
  int rB = wn * 64 + lr;
  int cofs0 = (quad ^ (lr & 7)) * 8;
  int cofs1 = ((4 | quad) ^ (lr & 7)) * 8;

  f32x4 zero = {0.f, 0.f, 0.f, 0.f};
  f32x4 acc[8][4];
#pragma unroll
  for (int i = 0; i < 8; i++)
#pragma unroll
    for (int j = 0; j < 4; j++) acc[i][j] = zero;

  bfrag8 af[4][2], bf[2][2];

  QKV_STAGE(0, 0);  // prologue: tile 0 in flight (8 loads)

#pragma unroll 1
  for (int kt = 0; kt < NT; kt++) {
    const u16* as_ = As[kt & 1];
    const u16* bs_ = Bs[kt & 1];
    // ---- P0: issue next tile's stages, counted wait for current tile ----
    if (kt + 1 < NT) {
      QKV_STAGE(kt + 1, (kt + 1) & 1);  // buf freed at P3(kt-1) barrier
      asm volatile("s_waitcnt vmcnt(8)" ::: "memory");  // tile kt landed; kt+1 in flight
      __builtin_amdgcn_sched_barrier(0);
    } else {
      asm volatile("s_waitcnt vmcnt(0)" ::: "memory");
      __builtin_amdgcn_sched_barrier(0);
    }
    block_barrier();  // tile kt's LDS writes globally visible
    QKV_LOADA(0);
    QKV_LOADB(0);
    QKV_MMA(0, 0);
    block_barrier();
    // ---- P1: reuse A0-3, new B2-3 ----
    QKV_LOADB(2);
    QKV_MMA(0, 2);
    block_barrier();
    // ---- P2: new A4-7, reuse B2-3 ----
    QKV_LOADA(4);
    QKV_MMA(4, 2);
    block_barrier();
    // ---- P3: reuse A4-7, new B0-1 ----
    QKV_LOADB(0);
    QKV_MMA(4, 0);
    block_barrier();  // all reads of buf[kt&1] done -> safe to restage at next P0
  }

  // epilogue: RoPE for q,k (cols are head-aligned per wave: span == 64 == head_dim)
  int colbase = n0 + wn * 64;
  int which = colbase >> 10;  // 0=q 1=k 2=v
  int h = (colbase & 1023) >> 6;
  u16* dst = which == 0 ? qb : (which == 1 ? kb : vb);
  float sc0 = (which == 0) ? 0.125f : 1.0f;
  float fr0 = __expf(-0.28782313662425574f * (float)lr);        // ln(10000)/32
  float fr1 = __expf(-0.28782313662425574f * (float)(16 + lr));
#pragma unroll
  for (int i = 0; i < 8; i++) {
#pragma unroll
    for (int r = 0; r < 4; r++) {
      int m = m0 + wm * 128 + i * 16 + quad * 4 + r;
      int b = m >> 11, tt = m & 2047;
      size_t base = ((size_t)(b * H_ + h) * T_ + tt) * D_;
      if (which < 2) {
        float sn, cs;
        __sincosf((float)tt * fr0, &sn, &cs);
        dst[base + lr] = f2bf((acc[i][0][r] * cs - acc[i][2][r] * sn) * sc0);
        dst[base + lr + 32] = f2bf((acc[i][0][r] * sn + acc[i][2][r] * cs) * sc0);
        __sincosf((float)tt * fr1, &sn, &cs);
        dst[base + 16 + lr] = f2bf((acc[i][1][r] * cs - acc[i][3][r] * sn) * sc0);
        dst[base + 48 + lr] = f2bf((acc[i][1][r] * sn + acc[i][3][r] * cs) * sc0);
      } else {
#pragma unroll
        for (int j = 0; j < 4; j++) dst[base + j * 16 + lr] = f2bf(acc[i][j][r]);
      }
    }
  }
}

// -------- transpose V: [b,h,t,d] -> [b,h,d,t] --------
__global__ __launch_bounds__(256) void transpose_v(const u16* __restrict__ v,
                                                   u16* __restrict__ vt) {
  __shared__ u16 tile[64][72];
  int t0 = blockIdx.x * 64;
  int bh = blockIdx.y;
  const u16* src = v + (size_t)bh * T_ * D_;
  u16* dst = vt + (size_t)bh * D_ * T_;
  for (int idx = threadIdx.x; idx < 512; idx += 256) {
    int r = idx >> 3, c8 = (idx & 7) * 8;
    *(uint4*)&tile[r][c8] = *(const uint4*)(src + (size_t)(t0 + r) * D_ + c8);
  }
  __syncthreads();
  for (int idx = threadIdx.x; idx < 512; idx += 256) {
    int d = idx >> 3, t8 = (idx & 7) * 8;
    union { uint4 u; u16 s[8]; } p;
#pragma unroll
    for (int e = 0; e < 8; e++) p.s[e] = tile[t8 + e][d];
    *(uint4*)(dst + (size_t)d * T_ + t0 + t8) = p.u;
  }
}

// -------- attention: causal, S^T formulation, q-tile 64 (16 rows/wave), kv-tile 64,
// dbuf + single barrier/iter, heavy-first blocks, XOR-swizzled K/V LDS layout. ----
__global__ __launch_bounds__(256) void attn_k(const u16* __restrict__ qb,
                                              const u16* __restrict__ kb,
                                              const u16* __restrict__ vtb,
                                              u16* __restrict__ ob) {
  __shared__ __align__(16) u16 Ks[2][64 * 64];   // [t][chunk^t&7]
  __shared__ __align__(16) u16 Vt[2][64 * 64];   // [d][chunk^d&7]
  __shared__ __align__(16) u16 Pst[4][16 * 72];  // per-wave P [q=16][t=64 +pad]
  int tid = threadIdx.x;
  int lane = tid & 63, wave = tid >> 6;
  int quad = lane >> 4, lr = lane & 15;
  int i = blockIdx.x;
  int bq = 31 - (i >> 5);  // heavy blocks dispatched first
  int bh = i & 31;
  int b = bh >> 4, h = bh & 15;
  const u16* Q = qb + (size_t)bh * T_ * D_;
  const u16* Kp = kb + (size_t)bh * T_ * D_;
  const u16* Vp = vtb + (size_t)bh * D_ * T_;
  int qr0 = bq * 64 + wave * 16;  // this wave's q-row base
  int r0 = wave * 16;             // staging row base
  int sr = lane >> 3;
  int sc = (((lane & 7) ^ (sr & 7)) * 8);  // XOR-swizzled staging column

  // read-side swizzled chunk offsets (u16 units), constant per lane
  int koff0 = ((quad ^ (lr & 7)) << 3);
  int koff1 = (((4 | quad) ^ (lr & 7)) << 3);

  // Q fragment as MFMA B-operand: B[n=q][k=d] (from global, unswizzled)
  bfrag8 qf[2];
#pragma unroll
  for (int ks = 0; ks < 2; ks++)
    qf[ks] = *(const bfrag8*)(Q + (size_t)(qr0 + lr) * D_ + ks * 32 + quad * 8);

  f32x4 zero = {0.f, 0.f, 0.f, 0.f};
  f32x4 o[4];
#pragma unroll
  for (int nn = 0; nn < 4; nn++) o[nn] = zero;
  float psum = 0.f;

  const u16* gk = Kp + (size_t)(r0 + sr) * D_ + sc;
  const u16* gv = Vp + (size_t)(r0 + sr) * T_ + sc;
  int niter = bq + 1;

  load_lds16(gk, &Ks[0][r0 * 64]);
  load_lds16(gk + (size_t)8 * D_, &Ks[0][(r0 + 8) * 64]);
  load_lds16(gv, &Vt[0][r0 * 64]);
  load_lds16(gv + (size_t)8 * T_, &Vt[0][(r0 + 8) * 64]);

  int buf = 0;
  int qloc = wave * 16 + lr;
  for (int it = 0; it < niter; it++) {
    __syncthreads();  // drains loads for tile `it` (issued one compute-phase ago)
    if (it + 1 < niter) {
      int tkn = (it + 1) * 64;
      load_lds16(gk + (size_t)tkn * D_, &Ks[buf ^ 1][r0 * 64]);
      load_lds16(gk + (size_t)(tkn + 8) * D_, &Ks[buf ^ 1][(r0 + 8) * 64]);
      load_lds16(gv + tkn, &Vt[buf ^ 1][r0 * 64]);
      load_lds16(gv + (size_t)8 * T_ + tkn, &Vt[buf ^ 1][(r0 + 8) * 64]);
    }
    const u16* ks_ = Ks[buf];
    const u16* vt_ = Vt[buf];

    // S^T = K Q^T : 64 kv-rows x 16 q-cols (A=K-frag swizzled, B=Q-frag)
    f32x4 s[4];
#pragma unroll
    for (int j = 0; j < 4; j++) s[j] = zero;
#pragma unroll
    for (int j = 0; j < 4; j++) {
      bfrag8 kf0 = *(const bfrag8*)&ks_[(j * 16 + lr) * 64 + koff0];
      bfrag8 kf1 = *(const bfrag8*)&ks_[(j * 16 + lr) * 64 + koff1];
      s[j] = MFMA_BF16(kf0, qf[0], s[j]);
      s[j] = MFMA_BF16(kf1, qf[1], s[j]);
    }

    // exp + pack pairs (RNE-ish) + ds_write_b64 to Pst[q][t]
    bool edge = (it == bq);  // wave-uniform
#pragma unroll
    for (int j = 0; j < 4; j++) {
      float p[4];
#pragma unroll
      for (int r = 0; r < 4; r++) {
        float e = __expf(s[j][r]);
        if (edge) {
          int kvloc = j * 16 + quad * 4 + r;
          e = (kvloc <= qloc) ? e : 0.f;
        }
        p[r] = e;
        psum += e;
      }
      u32 u0 = __builtin_bit_cast(u32, p[0]) + 0x8000u;
      u32 u1 = __builtin_bit_cast(u32, p[1]) + 0x8000u;
      u32 u2 = __builtin_bit_cast(u32, p[2]) + 0x8000u;
      u32 u3 = __builtin_bit_cast(u32, p[3]) + 0x8000u;
      uint2 pk;
      pk.x = (u0 >> 16) | (u1 & 0xffff0000u);
      pk.y = (u2 >> 16) | (u3 & 0xffff0000u);
      *(uint2*)&Pst[wave][lr * 72 + j * 16 + quad * 4] = pk;
    }

    // O += P V : A = P[q][t] (b128 from Pst), B = V^T[d][t] (swizzled)
#pragma unroll
    for (int ks = 0; ks < 2; ks++) {
      bfrag8 pf = *(const bfrag8*)&Pst[wave][lr * 72 + ks * 32 + quad * 8];
      int ko = ks ? koff1 : koff0;
#pragma unroll
      for (int nn = 0; nn < 4; nn++) {
        bfrag8 vf = *(const bfrag8*)&vt_[(nn * 16 + lr) * 64 + ko];
        o[nn] = MFMA_BF16(pf, vf, o[nn]);
      }
    }
    buf ^= 1;
  }

  // total row-sum: reduce over the 4 quads
  float l = psum;
  l += __shfl_xor(l, 16, 64);
  l += __shfl_xor(l, 32, 64);
  float linv = 1.0f / l;

#pragma unroll
  for (int r = 0; r < 4; r++) {
    float lrec = __shfl(linv, quad * 4 + r, 64);
    int row = qr0 + quad * 4 + r;
#pragma unroll
    for (int nn = 0; nn < 4; nn++)
      ob[(size_t)(b * T_ + row) * C_ + h * 64 + nn * 16 + lr] = f2bf(o[nn][r] * lrec);
  }
}

// -------- GEMM 2: out(f32) = A(4096x1024)bf16 @ WT(1024x1024)bf16 + bias(f32).
// 64x128 tile (grid 512), dbuf LDS, single barrier per iter. --------
__global__ __launch_bounds__(256) void gemm_proj(const u16* __restrict__ A,
                                                 const u16* __restrict__ WT,
                                                 const float* __restrict__ bias,
                                                 float* __restrict__ out) {
  const int K = C_;
  __shared__ __align__(16) u16 As[2][64 * 32];
  __shared__ __align__(16) u16 Bs[2][128 * 32];
  int tid = threadIdx.x;
  int lane = tid & 63, wave = tid >> 6;
  int quad = lane >> 4, lr = lane & 15;
  int m0 = blockIdx.y * 64, n0 = blockIdx.x * 128;
  int wcol = wave * 32;
  int srow = lane >> 2, skc = (lane & 3) * 8;

  f32x4 zero = {0.f, 0.f, 0.f, 0.f};
  f32x4 acc[4][2];
#pragma unroll
  for (int i = 0; i < 4; i++)
#pragma unroll
    for (int j = 0; j < 2; j++) acc[i][j] = zero;

  const u16* ga = A + (size_t)(m0 + wave * 16 + srow) * K + skc;
  const u16* gb0 = WT + (size_t)(n0 + wave * 32 + srow) * K + skc;
  const u16* gb1 = WT + (size_t)(n0 + wave * 32 + 16 + srow) * K + skc;

  load_lds16(ga, &As[0][wave * 16 * 32]);
  load_lds16(gb0, &Bs[0][wave * 32 * 32]);
  load_lds16(gb1, &Bs[0][(wave * 32 + 16) * 32]);

  int buf = 0;
  for (int k0 = 0; k0 < K; k0 += 32) {
    __syncthreads();
    if (k0 + 32 < K) {
      load_lds16(ga + k0 + 32, &As[buf ^ 1][wave * 16 * 32]);
      load_lds16(gb0 + k0 + 32, &Bs[buf ^ 1][wave * 32 * 32]);
      load_lds16(gb1 + k0 + 32, &Bs[buf ^ 1][(wave * 32 + 16) * 32]);
    }
    bfrag8 af[4], bfr[2];
#pragma unroll
    for (int i = 0; i < 4; i++)
      af[i] = *(const bfrag8*)&As[buf][(i * 16 + lr) * 32 + quad * 8];
#pragma unroll
    for (int j = 0; j < 2; j++)
      bfr[j] = *(const bfrag8*)&Bs[buf][(wcol + j * 16 + lr) * 32 + quad * 8];
#pragma unroll
    for (int i = 0; i < 4; i++)
#pragma unroll
      for (int j = 0; j < 2; j++) acc[i][j] = MFMA_BF16(af[i], bfr[j], acc[i][j]);
    buf ^= 1;
  }

#pragma unroll
  for (int i = 0; i < 4; i++)
#pragma unroll
    for (int r = 0; r < 4; r++) {
      int m = m0 + i * 16 + quad * 4 + r;
#pragma unroll
      for (int j = 0; j < 2; j++) {
        int n = n0 + wcol + j * 16 + lr;
        out[(size_t)m * C_ + n] = acc[i][j][r] + bias[n];
      }
    }
}

extern "C" void kernel_launch(void* const* d_in, const int* in_sizes, int n_in,
                              void* d_out, int out_size, void* d_ws, size_t ws_size,
                              hipStream_t stream) {
  const float* x = (const float*)d_in[0];       // [4096,1024] f32
  const float* w_qkv = (const float*)d_in[1];   // [1024,3072] f32
  const float* w_proj = (const float*)d_in[2];  // [1024,1024] f32
  const float* b_proj = (const float*)d_in[3];  // [1024] f32

  char* w = (char*)d_ws;
  u16* xb = (u16*)(w + 256);                 // 4096*1024 bf16
  u16* vtb = xb;                             // alias: used after xb is dead
  u16* regA = xb + (size_t)4096 * 1024;      // max(wqkvT, abuf)
  u16* wqkvT = regA;                         // 3072*1024 (dead after gemm_qkv)
  u16* abuf = regA;                          // 4096*1024 (written by attn)
  u16* wprojT = regA + (size_t)4096 * 1024;  // 1024*1024
  u16* qbuf = wprojT + (size_t)1024 * 1024;
  u16* kbuf = qbuf + (size_t)B_ * H_ * T_ * D_;
  u16* vbuf = kbuf + (size_t)B_ * H_ * T_ * D_;

  convert_x<<<2048, 256, 0, stream>>>(x, xb);
  transpose_w<<<dim3(NQKV_ / 64, C_ / 64), 256, 0, stream>>>(w_qkv, wqkvT, C_, NQKV_);
  transpose_w<<<dim3(C_ / 64, C_ / 64), 256, 0, stream>>>(w_proj, wprojT, C_, C_);
  gemm_qkv_rope<<<dim3(NQKV_ / 256, (B_ * T_) / 256), 512, 0, stream>>>(xb, wqkvT, qbuf, kbuf, vbuf);
  transpose_v<<<dim3(T_ / 64, B_ * H_), 256, 0, stream>>>(vbuf, vtb);
  attn_k<<<1024, 256, 0, stream>>>(qbuf, kbuf, vtb, abuf);
  gemm_proj<<<dim3(C_ / 128, (B_ * T_) / 64), 256, 0, stream>>>(abuf, wprojT, b_proj, (float*)d_out);
}